// Round 6
// baseline (570.162 us; speedup 1.0000x reference)
//
#include <hip/hip_runtime.h>
#include <stdint.h>

typedef float f32x4  __attribute__((ext_vector_type(4)));
typedef float f32x16 __attribute__((ext_vector_type(16)));
typedef int   i32x4  __attribute__((ext_vector_type(4)));
typedef int   i32x8  __attribute__((ext_vector_type(8)));

constexpr int Mdim = 8192;    // B*S = 4*2048
constexpr int Ndim = 14336;
constexpr int Kdim = 4096;
constexpr int BM = 256, BN = 256, BK = 64;
constexpr int NT = Kdim / BK;          // 64 K-iterations
constexpr uint32_t SLOT = 32768;       // ring slot: A(16K) + B(16K)

#define VMCNT(n) asm volatile("s_waitcnt vmcnt(" #n ")" ::: "memory")
#define LGKM(n)  do { asm volatile("s_waitcnt lgkmcnt(" #n ")" ::: "memory"); \
                      __builtin_amdgcn_sched_barrier(0); } while (0)
#define BARRIER() do { asm volatile("" ::: "memory"); \
                       __builtin_amdgcn_s_barrier(); \
                       asm volatile("" ::: "memory"); } while (0)

__device__ __forceinline__ void gload_lds16(const void* g, void* l) {
  __builtin_amdgcn_global_load_lds(
      (const __attribute__((address_space(1))) unsigned int*)g,
      (__attribute__((address_space(3))) unsigned int*)l, 16, 0, 0);
}

__device__ __forceinline__ i32x4 ldsr128(const uint8_t* p) {
  i32x4 r;
  asm volatile("ds_read_b128 %0, %1"
               : "=v"(r)
               : "v"((const __attribute__((address_space(3))) uint8_t*)p));
  return r;
}

// Fragment read, 64-B rows: lane needs logical bytes [kh*32, kh*32+32) of its
// row.  T2 swizzle: physical 16B-block = logical ^ ((row>>1)&3).  Uniformity:
// bank-group g = 4(row&1) + pc hits each of 8 groups exactly 8x per wave64
// b128 read (b128 floor) for both the lo and hi read.
__device__ __forceinline__ i32x8 frag(const uint8_t* tile, int row, int kh) {
  const int p0 = (kh * 32) ^ (((row >> 1) & 3) << 4);
  const uint8_t* rp = tile + row * 64;
  i32x4 lo = ldsr128(rp + p0);
  i32x4 hi = ldsr128(rp + (p0 ^ 16));
  return __builtin_shufflevector(lo, hi, 0, 1, 2, 3, 4, 5, 6, 7);
}

__device__ __forceinline__ f32x16 mx(i32x8 a, i32x8 b, f32x16 c) {
  // unit e8m0 scales (0x7f = 2^0): bit-identical to plain fp8 matmul, 2x rate
  return __builtin_amdgcn_mfma_scale_f32_32x32x64_f8f6f4(
      a, b, c, 0, 0, 0, 0x7f7f7f7f, 0, 0x7f7f7f7f);
}

// Quantize fp32 -> fp8 e4m3fn (OCP, RNE via v_cvt_pk_fp8_f32):
//   q = cast(clip(v / s, -448, 448)).  Weight path: scale_ptr==nullptr.
__global__ void __launch_bounds__(256) quant_fp8_kernel(
    const float* __restrict__ in, uint8_t* __restrict__ out8,
    const float* __restrict__ scale_ptr, long long n)
{
  const float s = scale_ptr ? scale_ptr[0] : 1.0f;
  const long long nch = n >> 3;
  const long long idx = (long long)blockIdx.x * blockDim.x + threadIdx.x;
  const long long stride = (long long)gridDim.x * blockDim.x;
  for (long long c = idx; c < nch; c += stride) {
    f32x4 v0 = *(const f32x4*)(in + c * 8);
    f32x4 v1 = *(const f32x4*)(in + c * 8 + 4);
    float q[8];
#pragma unroll
    for (int j = 0; j < 4; ++j) {
      q[j]     = fminf(fmaxf(v0[j] / s, -448.f), 448.f);
      q[4 + j] = fminf(fmaxf(v1[j] / s, -448.f), 448.f);
    }
    unsigned int w0 = 0, w1 = 0;
    w0 = __builtin_amdgcn_cvt_pk_fp8_f32(q[0], q[1], w0, false);
    w0 = __builtin_amdgcn_cvt_pk_fp8_f32(q[2], q[3], w0, true);
    w1 = __builtin_amdgcn_cvt_pk_fp8_f32(q[4], q[5], w1, false);
    w1 = __builtin_amdgcn_cvt_pk_fp8_f32(q[6], q[7], w1, true);
    uint2 r; r.x = w0; r.y = w1;
    *(uint2*)(out8 + c * 8) = r;
  }
}

// C = (A @ B^T) * alpha + bias, MX-fp8 unit-scale MFMA.
// 256x256 tile, BK=64 iterations, 8 waves (2M x 4N), per-wave 128x64 = 4x2
// frags of 32x32x64.  4-slot LDS ring (32 KiB each, 128 KiB total): iter t
// computes buf[t&3] while staging iter t+3 into buf[(t+3)&3] (= the slot all
// waves finished reading before this iter's barrier).  Prefetch distance
// ~2.5 iterations (~2750 cyc) >> HBM-miss latency (~900 cyc), so the head
// VMCNT(8) (keeps iters t+1,t+2 in flight — counted, T4) never stalls in
// steady state.  ONE barrier per iteration.  Counted lgkm frag pipeline:
// issue 12 ds_reads, LGKM(4) -> first 8 ready -> 4 MFMA, LGKM(0) -> 4 MFMA,
// setprio around MFMA clusters (T5).  Tail: VMCNT(4)/VMCNT(0) peel.
//
// T2 swizzle (64-B rows): physical 16B-block = logical ^ ((row>>1)&3);
// pre-swizzled GLOBAL source + linear gload_lds dest + XOR on read (rule #21).
__global__ void __launch_bounds__(512, 2) gemm_fp8_kernel(
    const uint8_t* __restrict__ qa, const uint8_t* __restrict__ qb,
    const float* __restrict__ iscale, const float* __restrict__ wscale,
    const float* __restrict__ bias, float* __restrict__ out)
{
  __shared__ uint8_t smem[4 * SLOT];   // 128 KiB

  const int tid  = threadIdx.x;
  const int wave = tid >> 6;
  const int lane = tid & 63;
  const int wm   = wave >> 2;       // 0..1
  const int wn   = wave & 3;        // 0..3
  const int col  = lane & 31;
  const int kh   = lane >> 5;
  const long long tile_m = (long long)blockIdx.y * BM;
  const long long tile_n = (long long)blockIdx.x * BN;

  // Staging: slot = A(2 units) + B(2 units); unit = 128 rows x 64 B = 8 KiB
  // = 512 thr x 16 B.  Thread -> unit-row tid>>2, physical block tid&3;
  // global source block = pb ^ ((row>>1)&3), row ≡ tid>>2 (mod 8 safe: units
  // start at multiples of 128).
  const int urow = tid >> 2;                   // 0..127
  const int pbs  = tid & 3;
  const int scol = (pbs ^ ((urow >> 1) & 3)) << 4;
  const uint8_t* gA = qa + (tile_m + urow) * Kdim + scol;
  const uint8_t* gB = qb + (tile_n + urow) * Kdim + scol;
  uint8_t* lbase = smem + wave * 1024;         // wave-uniform; + lane*16 by HW

  // unit u of matrix mat for K-iter tt into ring slot boff
#define STAGE(u, mat, tt, boff)                                            \
  gload_lds16((mat ? gB : gA) + (long long)(u) * 128 * Kdim +              \
                  (long long)(tt) * BK,                                    \
              lbase + (boff) + (mat) * 16384 + (u) * 8192)

  f32x16 acc[4][2] = {};

  const int rowA = wm * 128 + col;   // + m*32
  const int rowB = wn * 64 + col;    // + n*32

  // prologue: stage iters 0,1,2 into slots 0,1,2 (12 loads in flight)
#pragma unroll
  for (int tt = 0; tt < 3; ++tt) {
    STAGE(0, 0, tt, (uint32_t)tt * SLOT); STAGE(1, 0, tt, (uint32_t)tt * SLOT);
    STAGE(0, 1, tt, (uint32_t)tt * SLOT); STAGE(1, 1, tt, (uint32_t)tt * SLOT);
  }

  for (int t = 0; t < NT; ++t) {
    const uint8_t* Ab = smem + (uint32_t)(t & 3) * SLOT;
    const uint8_t* Bb = Ab + 16384;

    // counted vmcnt: ensure iter t's 4 loads retired, keep newer in flight
    if (t + 2 < NT)      { VMCNT(8); }
    else if (t + 1 < NT) { VMCNT(4); }
    else                 { VMCNT(0); }
    BARRIER();   // t's data visible to all waves; slot (t+3)&3 free

    if (t + 3 < NT) {
      const uint32_t bo = (uint32_t)((t + 3) & 3) * SLOT;
      STAGE(0, 0, t + 3, bo); STAGE(1, 0, t + 3, bo);
      STAGE(0, 1, t + 3, bo); STAGE(1, 1, t + 3, bo);
    }

    // issue 12 ds_reads: first 8 feed MFMA cluster 1
    i32x8 A0 = frag(Ab, rowA +  0, kh);
    i32x8 A1 = frag(Ab, rowA + 32, kh);
    i32x8 B0 = frag(Bb, rowB +  0, kh);
    i32x8 B1 = frag(Bb, rowB + 32, kh);
    i32x8 A2 = frag(Ab, rowA + 64, kh);
    i32x8 A3 = frag(Ab, rowA + 96, kh);

    LGKM(4);              // A0,A1,B0,B1 ready; A2,A3 in flight
    __builtin_amdgcn_s_setprio(1);
    acc[0][0] = mx(A0, B0, acc[0][0]);  acc[0][1] = mx(A0, B1, acc[0][1]);
    acc[1][0] = mx(A1, B0, acc[1][0]);  acc[1][1] = mx(A1, B1, acc[1][1]);
    __builtin_amdgcn_s_setprio(0);
    LGKM(0);              // A2,A3 ready
    __builtin_amdgcn_s_setprio(1);
    acc[2][0] = mx(A2, B0, acc[2][0]);  acc[2][1] = mx(A2, B1, acc[2][1]);
    acc[3][0] = mx(A3, B0, acc[3][0]);  acc[3][1] = mx(A3, B1, acc[3][1]);
    __builtin_amdgcn_s_setprio(0);
  }

  // Epilogue.  C/D layout (32x32, dtype-independent): col = lane&31,
  // row = (r&3) + 8*(r>>2) + 4*kh, r in [0,16).
  const float alpha = iscale[0] * wscale[0];
  const long long col0 = tile_n + wn * 64 + col;
  const float bv0 = bias[col0];
  const float bv1 = bias[col0 + 32];
#pragma unroll
  for (int m = 0; m < 4; ++m) {
#pragma unroll
    for (int r = 0; r < 16; ++r) {
      const long long row =
          tile_m + wm * 128 + m * 32 + (r & 3) + 8 * (r >> 2) + 4 * kh;
      float* op = out + row * (long long)Ndim + col0;
      op[0]  = acc[m][0][r] * alpha + bv0;
      op[32] = acc[m][1][r] * alpha + bv1;
    }
  }
#undef STAGE
}

extern "C" void kernel_launch(void* const* d_in, const int* in_sizes, int n_in,
                              void* d_out, int out_size, void* d_ws, size_t ws_size,
                              hipStream_t stream) {
  const float* x      = (const float*)d_in[0];  // [4,2048,4096]
  const float* weight = (const float*)d_in[1];  // [14336,4096] (e4m3 lattice)
  const float* wscale = (const float*)d_in[2];  // [1]
  const float* iscale = (const float*)d_in[3];  // [1]
  const float* bias   = (const float*)d_in[4];  // [14336]
  float* out = (float*)d_out;                   // [4,2048,14336]

  uint8_t* qx = (uint8_t*)d_ws;                          // 32 MiB
  uint8_t* qw = qx + (long long)Mdim * Kdim;             // 56 MiB

  const long long nx = (long long)Mdim * Kdim;
  const long long nw = (long long)Ndim * Kdim;

  quant_fp8_kernel<<<4096, 256, 0, stream>>>(x, qx, iscale, nx);
  quant_fp8_kernel<<<4096, 256, 0, stream>>>(weight, qw, nullptr, nw);

  dim3 grid(Ndim / BN, Mdim / BM);   // 56 x 32
  gemm_fp8_kernel<<<grid, 512, 0, stream>>>(qx, qw, iscale, wscale, bias, out);
}

// Round 7
// 550.770 us; speedup vs baseline: 1.0352x; 1.0352x over previous
//
#include <hip/hip_runtime.h>
#include <stdint.h>

typedef float f32x4  __attribute__((ext_vector_type(4)));
typedef float f32x16 __attribute__((ext_vector_type(16)));
typedef int   i32x4  __attribute__((ext_vector_type(4)));
typedef int   i32x8  __attribute__((ext_vector_type(8)));

constexpr int Mdim = 8192;    // B*S = 4*2048
constexpr int Ndim = 14336;
constexpr int Kdim = 4096;
constexpr int BM = 256, BN = 256, BK = 128;
constexpr int NT = Kdim / BK;        // 32 K-tiles
constexpr uint32_t BUFSZ = 65536;    // one buffer: A(32K) + B(32K)

#define VMCNT(n) asm volatile("s_waitcnt vmcnt(" #n ")" ::: "memory")
#define LGKM(n)  do { asm volatile("s_waitcnt lgkmcnt(" #n ")" ::: "memory"); \
                      __builtin_amdgcn_sched_barrier(0); } while (0)
#define BARRIER() do { asm volatile("" ::: "memory"); \
                       __builtin_amdgcn_s_barrier(); \
                       asm volatile("" ::: "memory"); } while (0)

__device__ __forceinline__ void gload_lds16(const void* g, void* l) {
  __builtin_amdgcn_global_load_lds(
      (const __attribute__((address_space(1))) unsigned int*)g,
      (__attribute__((address_space(3))) unsigned int*)l, 16, 0, 0);
}

__device__ __forceinline__ i32x4 ldsr128(const uint8_t* p) {
  i32x4 r;
  asm volatile("ds_read_b128 %0, %1"
               : "=v"(r)
               : "v"((const __attribute__((address_space(3))) uint8_t*)p));
  return r;
}

// Fragment read: 32 contiguous logical bytes (one 32x32x64 A/B frag per lane)
// at logical byte kb of row `row`; physical byte = logical ^ ((row&7)<<4).
__device__ __forceinline__ i32x8 frag(const uint8_t* tile, int row, int kb) {
  const int p0 = kb ^ ((row & 7) << 4);
  const uint8_t* rp = tile + row * BK;
  i32x4 lo = ldsr128(rp + p0);
  i32x4 hi = ldsr128(rp + (p0 ^ 16));
  return __builtin_shufflevector(lo, hi, 0, 1, 2, 3, 4, 5, 6, 7);
}

__device__ __forceinline__ f32x16 mx(i32x8 a, i32x8 b, f32x16 c) {
  // unit e8m0 scales (0x7f = 2^0): bit-identical to plain fp8 matmul, 2x rate
  return __builtin_amdgcn_mfma_scale_f32_32x32x64_f8f6f4(
      a, b, c, 0, 0, 0, 0x7f7f7f7f, 0, 0x7f7f7f7f);
}

// Quantize fp32 -> fp8 e4m3fn (OCP, RNE via v_cvt_pk_fp8_f32):
//   q = cast(clip(v / s, -448, 448)).  Weight path: scale_ptr==nullptr.
__global__ void __launch_bounds__(256) quant_fp8_kernel(
    const float* __restrict__ in, uint8_t* __restrict__ out8,
    const float* __restrict__ scale_ptr, long long n)
{
  const float s = scale_ptr ? scale_ptr[0] : 1.0f;
  const long long nch = n >> 3;
  const long long idx = (long long)blockIdx.x * blockDim.x + threadIdx.x;
  const long long stride = (long long)gridDim.x * blockDim.x;
  for (long long c = idx; c < nch; c += stride) {
    f32x4 v0 = *(const f32x4*)(in + c * 8);
    f32x4 v1 = *(const f32x4*)(in + c * 8 + 4);
    float q[8];
#pragma unroll
    for (int j = 0; j < 4; ++j) {
      q[j]     = fminf(fmaxf(v0[j] / s, -448.f), 448.f);
      q[4 + j] = fminf(fmaxf(v1[j] / s, -448.f), 448.f);
    }
    unsigned int w0 = 0, w1 = 0;
    w0 = __builtin_amdgcn_cvt_pk_fp8_f32(q[0], q[1], w0, false);
    w0 = __builtin_amdgcn_cvt_pk_fp8_f32(q[2], q[3], w0, true);
    w1 = __builtin_amdgcn_cvt_pk_fp8_f32(q[4], q[5], w1, false);
    w1 = __builtin_amdgcn_cvt_pk_fp8_f32(q[6], q[7], w1, true);
    uint2 r; r.x = w0; r.y = w1;
    *(uint2*)(out8 + c * 8) = r;
  }
}

// C = (A @ B^T) * alpha + bias, MX-fp8 unit-scale MFMA.
// 256x256 tile, BK=128, 8 waves (2M x 4N), per-wave 128x64 = 4x2 frags of
// 32x32x64.  m201-style DUAL-BARRIER 4-phase schedule: each phase =
// {issue frag ds_reads + 1 STAGE pair -> open barrier -> lgkm(0) ->
//  setprio(1) 4xMFMA setprio(0) -> close barrier}.  The close barrier
// phase-locks all 8 waves into strict read-issue/MFMA alternation (the
// measured-best m196/m201 structure).  Counted vmcnt(2) staging (T4): only
// P0 waits, and tile t+1's first 2 loads stay in flight across it.
//
// LDS: 2 buffers x (A 256x128 | B 256x128) = 128 KiB, linear rows,
// T2 swizzle: physical 16B-block = logical ^ (row&7); pre-swizzled GLOBAL
// source + linear gload_lds dest + XOR on read (rule #21).
__global__ void __launch_bounds__(512, 2) gemm_fp8_kernel(
    const uint8_t* __restrict__ qa, const uint8_t* __restrict__ qb,
    const float* __restrict__ iscale, const float* __restrict__ wscale,
    const float* __restrict__ bias, float* __restrict__ out)
{
  __shared__ uint8_t smem[2 * BUFSZ];   // 128 KiB

  const int tid  = threadIdx.x;
  const int wave = tid >> 6;
  const int lane = tid & 63;
  const int wm   = wave >> 2;       // 0..1
  const int wn   = wave & 3;        // 0..3
  const int col  = lane & 31;
  const int kh   = lane >> 5;
  const long long tile_m = (long long)blockIdx.y * BM;
  const long long tile_n = (long long)blockIdx.x * BN;

  // Staging: unit = 64 rows x 128 B = 8 KiB = 512 thr x 16 B (1 gload/thr).
  // Thread -> row tid>>3, physical block tid&7; source block = pb ^ (row&7).
  const int urow = tid >> 3;                   // 0..63
  const int pbs  = tid & 7;
  const int scol = (pbs ^ (urow & 7)) << 4;
  const uint8_t* gA = qa + (tile_m + urow) * Kdim + scol;
  const uint8_t* gB = qb + (tile_n + urow) * Kdim + scol;
  uint8_t* lbase = smem + wave * 1024;         // wave-uniform; + lane*16 by HW

#define STAGE(u, mat, k0, boff)                                           \
  gload_lds16((mat ? gB : gA) + (long long)(u) * 64 * Kdim + (k0),        \
              lbase + (boff) + (mat) * 32768 + (u) * 8192)

  f32x16 acc[4][2] = {};

  const int rowA = wm * 128 + col;   // + m*32
  const int rowB = wn * 64 + col;    // + n*32
  const int kb0 = kh * 32;           // ks=0 logical byte
  const int kb1 = 64 + kh * 32;      // ks=1

  // prologue: stage tile 0 into buffer 0 (8 loads in flight)
#pragma unroll
  for (int u = 0; u < 4; ++u) STAGE(u, 0, 0, 0);
#pragma unroll
  for (int u = 0; u < 4; ++u) STAGE(u, 1, 0, 0);

  uint32_t cur = 0;
  for (int t = 0; t < NT - 1; ++t) {
    const long long kn = (long long)(t + 1) * BK;
    const uint32_t nxt = cur ^ BUFSZ;
    const uint8_t* Ab = smem + cur;
    const uint8_t* Bb = smem + cur + 32768;

    // ---- P0: ks0, m{0,1} ----
    STAGE(0, 0, kn, nxt); STAGE(1, 0, kn, nxt);
    VMCNT(2);             // tile t's 8 loads retired; t+1's 2 stay in flight
    BARRIER();            // buf[cur] visible to all waves (= P0 open barrier)
    i32x8 A0 = frag(Ab, rowA +  0, kb0);
    i32x8 A1 = frag(Ab, rowA + 32, kb0);
    i32x8 B0 = frag(Bb, rowB +  0, kb0);
    i32x8 B1 = frag(Bb, rowB + 32, kb0);
    STAGE(2, 0, kn, nxt); STAGE(3, 0, kn, nxt);
    LGKM(0);
    __builtin_amdgcn_s_setprio(1);
    acc[0][0] = mx(A0, B0, acc[0][0]);  acc[0][1] = mx(A0, B1, acc[0][1]);
    acc[1][0] = mx(A1, B0, acc[1][0]);  acc[1][1] = mx(A1, B1, acc[1][1]);
    __builtin_amdgcn_s_setprio(0);
    BARRIER();            // P0 close: all waves finish MFMA before P1 reads

    // ---- P1: ks0, m{2,3} ----
    i32x8 A2 = frag(Ab, rowA + 64, kb0);
    i32x8 A3 = frag(Ab, rowA + 96, kb0);
    STAGE(0, 1, kn, nxt); STAGE(1, 1, kn, nxt);
    BARRIER();            // P1 open
    LGKM(0);
    __builtin_amdgcn_s_setprio(1);
    acc[2][0] = mx(A2, B0, acc[2][0]);  acc[2][1] = mx(A2, B1, acc[2][1]);
    acc[3][0] = mx(A3, B0, acc[3][0]);  acc[3][1] = mx(A3, B1, acc[3][1]);
    __builtin_amdgcn_s_setprio(0);
    BARRIER();            // P1 close

    // ---- P2: ks1, m{0,1} ----
    i32x8 A0p = frag(Ab, rowA +  0, kb1);
    i32x8 A1p = frag(Ab, rowA + 32, kb1);
    i32x8 B0p = frag(Bb, rowB +  0, kb1);
    i32x8 B1p = frag(Bb, rowB + 32, kb1);
    STAGE(2, 1, kn, nxt); STAGE(3, 1, kn, nxt);
    BARRIER();            // P2 open
    LGKM(0);
    __builtin_amdgcn_s_setprio(1);
    acc[0][0] = mx(A0p, B0p, acc[0][0]);  acc[0][1] = mx(A0p, B1p, acc[0][1]);
    acc[1][0] = mx(A1p, B0p, acc[1][0]);  acc[1][1] = mx(A1p, B1p, acc[1][1]);
    __builtin_amdgcn_s_setprio(0);
    BARRIER();            // P2 close

    // ---- P3: ks1, m{2,3} ----
    i32x8 A2p = frag(Ab, rowA + 64, kb1);
    i32x8 A3p = frag(Ab, rowA + 96, kb1);
    BARRIER();            // P3 open
    LGKM(0);
    __builtin_amdgcn_s_setprio(1);
    acc[2][0] = mx(A2p, B0p, acc[2][0]);  acc[2][1] = mx(A2p, B1p, acc[2][1]);
    acc[3][0] = mx(A3p, B0p, acc[3][0]);  acc[3][1] = mx(A3p, B1p, acc[3][1]);
    __builtin_amdgcn_s_setprio(0);
    BARRIER();            // P3 close: all reads of buf[cur] done; t+1 may
                          // overwrite it
    cur = nxt;
  }

  // ---- tail tile NT-1 (no prefetch) ----
  {
    const uint8_t* Ab = smem + cur;
    const uint8_t* Bb = smem + cur + 32768;
    VMCNT(0);
    BARRIER();
    i32x8 A0 = frag(Ab, rowA +  0, kb0);
    i32x8 A1 = frag(Ab, rowA + 32, kb0);
    i32x8 B0 = frag(Bb, rowB +  0, kb0);
    i32x8 B1 = frag(Bb, rowB + 32, kb0);
    i32x8 A2 = frag(Ab, rowA + 64, kb0);
    i32x8 A3 = frag(Ab, rowA + 96, kb0);
    LGKM(4);
    acc[0][0] = mx(A0, B0, acc[0][0]);  acc[0][1] = mx(A0, B1, acc[0][1]);
    acc[1][0] = mx(A1, B0, acc[1][0]);  acc[1][1] = mx(A1, B1, acc[1][1]);
    i32x8 A0p = frag(Ab, rowA +  0, kb1);
    i32x8 A1p = frag(Ab, rowA + 32, kb1);
    i32x8 B0p = frag(Bb, rowB +  0, kb1);
    i32x8 B1p = frag(Bb, rowB + 32, kb1);
    LGKM(8);
    acc[2][0] = mx(A2, B0, acc[2][0]);  acc[2][1] = mx(A2, B1, acc[2][1]);
    acc[3][0] = mx(A3, B0, acc[3][0]);  acc[3][1] = mx(A3, B1, acc[3][1]);
    i32x8 A2p = frag(Ab, rowA + 64, kb1);
    i32x8 A3p = frag(Ab, rowA + 96, kb1);
    LGKM(4);
    acc[0][0] = mx(A0p, B0p, acc[0][0]);  acc[0][1] = mx(A0p, B1p, acc[0][1]);
    acc[1][0] = mx(A1p, B0p, acc[1][0]);  acc[1][1] = mx(A1p, B1p, acc[1][1]);
    LGKM(0);
    acc[2][0] = mx(A2p, B0p, acc[2][0]);  acc[2][1] = mx(A2p, B1p, acc[2][1]);
    acc[3][0] = mx(A3p, B0p, acc[3][0]);  acc[3][1] = mx(A3p, B1p, acc[3][1]);
  }

  // Epilogue.  C/D layout (32x32, dtype-independent): col = lane&31,
  // row = (r&3) + 8*(r>>2) + 4*kh, r in [0,16).
  const float alpha = iscale[0] * wscale[0];
  const long long col0 = tile_n + wn * 64 + col;
  const float bv0 = bias[col0];
  const float bv1 = bias[col0 + 32];
#pragma unroll
  for (int m = 0; m < 4; ++m) {
#pragma unroll
    for (int r = 0; r < 16; ++r) {
      const long long row =
          tile_m + wm * 128 + m * 32 + (r & 3) + 8 * (r >> 2) + 4 * kh;
      float* op = out + row * (long long)Ndim + col0;
      op[0]  = acc[m][0][r] * alpha + bv0;
      op[32] = acc[m][1][r] * alpha + bv1;
    }
  }
#undef STAGE
}

extern "C" void kernel_launch(void* const* d_in, const int* in_sizes, int n_in,
                              void* d_out, int out_size, void* d_ws, size_t ws_size,
                              hipStream_t stream) {
  const float* x      = (const float*)d_in[0];  // [4,2048,4096]
  const float* weight = (const float*)d_in[1];  // [14336,4096] (e4m3 lattice)
  const float* wscale = (const float*)d_in[2];  // [1]
  const float* iscale = (const float*)d_in[3];  // [1]
  const float* bias   = (const float*)d_in[4];  // [14336]
  float* out = (float*)d_out;                   // [4,2048,14336]

  uint8_t* qx = (uint8_t*)d_ws;                          // 32 MiB
  uint8_t* qw = qx + (long long)Mdim * Kdim;             // 56 MiB

  const long long nx = (long long)Mdim * Kdim;
  const long long nw = (long long)Ndim * Kdim;

  quant_fp8_kernel<<<4096, 256, 0, stream>>>(x, qx, iscale, nx);
  quant_fp8_kernel<<<4096, 256, 0, stream>>>(weight, qw, nullptr, nw);

  dim3 grid(Ndim / BN, Mdim / BM);   // 56 x 32
  gemm_fp8_kernel<<<grid, 512, 0, stream>>>(qx, qw, iscale, wscale, bias, out);
}

// Round 8
// 528.839 us; speedup vs baseline: 1.0781x; 1.0415x over previous
//
#include <hip/hip_runtime.h>
#include <stdint.h>

typedef float f32x4  __attribute__((ext_vector_type(4)));
typedef float f32x16 __attribute__((ext_vector_type(16)));
typedef int   i32x4  __attribute__((ext_vector_type(4)));
typedef int   i32x8  __attribute__((ext_vector_type(8)));

constexpr int Mdim = 8192;    // B*S = 4*2048
constexpr int Ndim = 14336;
constexpr int Kdim = 4096;
constexpr int BM = 256, BN = 256, BK = 128;
constexpr int NT = Kdim / BK;        // 32 K-tiles
constexpr uint32_t BUFSZ = 65536;    // one buffer: A(32K) + B(32K)

#define VMCNT(n) asm volatile("s_waitcnt vmcnt(" #n ")" ::: "memory")
#define LGKM(n)  do { asm volatile("s_waitcnt lgkmcnt(" #n ")" ::: "memory"); \
                      __builtin_amdgcn_sched_barrier(0); } while (0)
#define BARRIER() do { asm volatile("" ::: "memory"); \
                       __builtin_amdgcn_s_barrier(); \
                       asm volatile("" ::: "memory"); } while (0)

__device__ __forceinline__ void gload_lds16(const void* g, void* l) {
  __builtin_amdgcn_global_load_lds(
      (const __attribute__((address_space(1))) unsigned int*)g,
      (__attribute__((address_space(3))) unsigned int*)l, 16, 0, 0);
}

__device__ __forceinline__ i32x4 ldsr128(const uint8_t* p) {
  i32x4 r;
  asm volatile("ds_read_b128 %0, %1"
               : "=v"(r)
               : "v"((const __attribute__((address_space(3))) uint8_t*)p));
  return r;
}

// Fragment read: 32 contiguous logical bytes (one 32x32x64 A/B frag per lane)
// at logical byte kb of row `row`; physical byte = logical ^ ((row&7)<<4).
__device__ __forceinline__ i32x8 frag(const uint8_t* tile, int row, int kb) {
  const int p0 = kb ^ ((row & 7) << 4);
  const uint8_t* rp = tile + row * BK;
  i32x4 lo = ldsr128(rp + p0);
  i32x4 hi = ldsr128(rp + (p0 ^ 16));
  return __builtin_shufflevector(lo, hi, 0, 1, 2, 3, 4, 5, 6, 7);
}

__device__ __forceinline__ f32x16 mx(i32x8 a, i32x8 b, f32x16 c) {
  // unit e8m0 scales (0x7f = 2^0): bit-identical to plain fp8 matmul, 2x rate
  return __builtin_amdgcn_mfma_scale_f32_32x32x64_f8f6f4(
      a, b, c, 0, 0, 0, 0x7f7f7f7f, 0, 0x7f7f7f7f);
}

// Quantize fp32 -> fp8 e4m3fn (OCP, RNE via v_cvt_pk_fp8_f32):
//   q = cast(clip(v / s, -448, 448)).  Weight path: scale_ptr==nullptr.
__global__ void __launch_bounds__(256) quant_fp8_kernel(
    const float* __restrict__ in, uint8_t* __restrict__ out8,
    const float* __restrict__ scale_ptr, long long n)
{
  const float s = scale_ptr ? scale_ptr[0] : 1.0f;
  const long long nch = n >> 3;
  const long long idx = (long long)blockIdx.x * blockDim.x + threadIdx.x;
  const long long stride = (long long)gridDim.x * blockDim.x;
  for (long long c = idx; c < nch; c += stride) {
    f32x4 v0 = *(const f32x4*)(in + c * 8);
    f32x4 v1 = *(const f32x4*)(in + c * 8 + 4);
    float q[8];
#pragma unroll
    for (int j = 0; j < 4; ++j) {
      q[j]     = fminf(fmaxf(v0[j] / s, -448.f), 448.f);
      q[4 + j] = fminf(fmaxf(v1[j] / s, -448.f), 448.f);
    }
    unsigned int w0 = 0, w1 = 0;
    w0 = __builtin_amdgcn_cvt_pk_fp8_f32(q[0], q[1], w0, false);
    w0 = __builtin_amdgcn_cvt_pk_fp8_f32(q[2], q[3], w0, true);
    w1 = __builtin_amdgcn_cvt_pk_fp8_f32(q[4], q[5], w1, false);
    w1 = __builtin_amdgcn_cvt_pk_fp8_f32(q[6], q[7], w1, true);
    uint2 r; r.x = w0; r.y = w1;
    *(uint2*)(out8 + c * 8) = r;
  }
}

// C = (A @ B^T) * alpha + bias, MX-fp8 unit-scale MFMA.
// 256x256 tile, BK=128, 8 waves (2M x 4N), per-wave 128x64 = 4x2 frags of
// 32x32x64.  R4 structure (2 barriers/tile, counted vmcnt(2) staging, T4/T5)
// + counted-lgkmcnt FRAGMENT pipeline (unconfounded retest of R5's mechanism,
// now WITHOUT the XCD swizzle that doubled FETCH): phase p+1's ds_reads issue
// before phase p's MFMA; each wait drains only what phase p needs (DS retires
// in order): [P0:8][P1:4] lgkm(4)->P0 | [P2:8] lgkm(8)->P1 | [P3:4]
// lgkm(4)->P2 | lgkm(0)->P3.  End-of-tile barrier moved BEFORE the last MFMA
// cluster (operands already in VGPRs; lgkm(0) drained all buf[cur] reads), so
// P3's MFMAs overlap the next tile's STAGE-issue + VMCNT wait in other waves.
//
// LDS: 2 buffers x (A 256x128 | B 256x128) = 128 KiB, linear rows,
// T2 swizzle: physical 16B-block = logical ^ (row&7); pre-swizzled GLOBAL
// source + linear gload_lds dest + XOR on read (rule #21).
__global__ void __launch_bounds__(512, 2) gemm_fp8_kernel(
    const uint8_t* __restrict__ qa, const uint8_t* __restrict__ qb,
    const float* __restrict__ iscale, const float* __restrict__ wscale,
    const float* __restrict__ bias, float* __restrict__ out)
{
  __shared__ uint8_t smem[2 * BUFSZ];   // 128 KiB

  const int tid  = threadIdx.x;
  const int wave = tid >> 6;
  const int lane = tid & 63;
  const int wm   = wave >> 2;       // 0..1
  const int wn   = wave & 3;        // 0..3
  const int col  = lane & 31;
  const int kh   = lane >> 5;
  const long long tile_m = (long long)blockIdx.y * BM;
  const long long tile_n = (long long)blockIdx.x * BN;

  // Staging: unit = 64 rows x 128 B = 8 KiB = 512 thr x 16 B (1 gload/thr).
  // Thread -> row tid>>3, physical block tid&7; source block = pb ^ (row&7).
  const int urow = tid >> 3;                   // 0..63
  const int pbs  = tid & 7;
  const int scol = (pbs ^ (urow & 7)) << 4;
  const uint8_t* gA = qa + (tile_m + urow) * Kdim + scol;
  const uint8_t* gB = qb + (tile_n + urow) * Kdim + scol;
  uint8_t* lbase = smem + wave * 1024;         // wave-uniform; + lane*16 by HW

#define STAGE(u, mat, k0, boff)                                           \
  gload_lds16((mat ? gB : gA) + (long long)(u) * 64 * Kdim + (k0),        \
              lbase + (boff) + (mat) * 32768 + (u) * 8192)

  f32x16 acc[4][2] = {};

  const int rowA = wm * 128 + col;   // + m*32
  const int rowB = wn * 64 + col;    // + n*32
  const int kb0 = kh * 32;           // ks=0 logical byte
  const int kb1 = 64 + kh * 32;      // ks=1

  // prologue: stage tile 0 into buffer 0 (8 loads in flight)
#pragma unroll
  for (int u = 0; u < 4; ++u) STAGE(u, 0, 0, 0);
#pragma unroll
  for (int u = 0; u < 4; ++u) STAGE(u, 1, 0, 0);

  uint32_t cur = 0;
  for (int t = 0; t < NT - 1; ++t) {
    const long long kn = (long long)(t + 1) * BK;
    const uint32_t nxt = cur ^ BUFSZ;
    const uint8_t* Ab = smem + cur;
    const uint8_t* Bb = smem + cur + 32768;

    STAGE(0, 0, kn, nxt); STAGE(1, 0, kn, nxt);
    VMCNT(2);             // tile t's 8 loads retired; t+1's 2 stay in flight
    BARRIER();            // buf[cur] tile-t data visible to all waves

    // P0 issue (8 ds_reads): ks0 m{0,1} + B pair
    i32x8 A0 = frag(Ab, rowA +  0, kb0);
    i32x8 A1 = frag(Ab, rowA + 32, kb0);
    i32x8 B0 = frag(Bb, rowB +  0, kb0);
    i32x8 B1 = frag(Bb, rowB + 32, kb0);
    STAGE(2, 0, kn, nxt); STAGE(3, 0, kn, nxt);
    // P1 issue (4): ks0 m{2,3}
    i32x8 A2 = frag(Ab, rowA + 64, kb0);
    i32x8 A3 = frag(Ab, rowA + 96, kb0);
    LGKM(4);              // P0 frags ready; P1's 4 reads still in flight
    __builtin_amdgcn_s_setprio(1);
    acc[0][0] = mx(A0, B0, acc[0][0]);  acc[0][1] = mx(A0, B1, acc[0][1]);
    acc[1][0] = mx(A1, B0, acc[1][0]);  acc[1][1] = mx(A1, B1, acc[1][1]);
    __builtin_amdgcn_s_setprio(0);

    STAGE(0, 1, kn, nxt); STAGE(1, 1, kn, nxt);
    // P2 issue (8): ks1 m{0,1} + B pair (primed set)
    i32x8 A0p = frag(Ab, rowA +  0, kb1);
    i32x8 A1p = frag(Ab, rowA + 32, kb1);
    i32x8 B0p = frag(Bb, rowB +  0, kb1);
    i32x8 B1p = frag(Bb, rowB + 32, kb1);
    LGKM(8);              // P1 frags ready; P2's 8 in flight
    __builtin_amdgcn_s_setprio(1);
    acc[2][0] = mx(A2, B0, acc[2][0]);  acc[2][1] = mx(A2, B1, acc[2][1]);
    acc[3][0] = mx(A3, B0, acc[3][0]);  acc[3][1] = mx(A3, B1, acc[3][1]);
    __builtin_amdgcn_s_setprio(0);

    STAGE(2, 1, kn, nxt); STAGE(3, 1, kn, nxt);
    // P3 issue (4): ks1 m{2,3}
    i32x8 A2p = frag(Ab, rowA + 64, kb1);
    i32x8 A3p = frag(Ab, rowA + 96, kb1);
    LGKM(4);              // P2 frags ready; P3's 4 in flight
    __builtin_amdgcn_s_setprio(1);
    acc[0][0] = mx(A0p, B0p, acc[0][0]);  acc[0][1] = mx(A0p, B1p, acc[0][1]);
    acc[1][0] = mx(A1p, B0p, acc[1][0]);  acc[1][1] = mx(A1p, B1p, acc[1][1]);
    __builtin_amdgcn_s_setprio(0);
    LGKM(0);              // P3 frags ready; ALL my reads of buf[cur] done
    BARRIER();            // moved up: every wave past lgkm(0) -> all reads of
                          // buf[cur] complete; next tile may overwrite it.
    __builtin_amdgcn_s_setprio(1);
    acc[2][0] = mx(A2p, B0p, acc[2][0]);  acc[2][1] = mx(A2p, B1p, acc[2][1]);
    acc[3][0] = mx(A3p, B0p, acc[3][0]);  acc[3][1] = mx(A3p, B1p, acc[3][1]);
    __builtin_amdgcn_s_setprio(0);

    cur = nxt;
  }

  // ---- tail tile NT-1 (no prefetch), same lgkm pipeline ----
  {
    const uint8_t* Ab = smem + cur;
    const uint8_t* Bb = smem + cur + 32768;
    VMCNT(0);
    BARRIER();
    i32x8 A0 = frag(Ab, rowA +  0, kb0);
    i32x8 A1 = frag(Ab, rowA + 32, kb0);
    i32x8 B0 = frag(Bb, rowB +  0, kb0);
    i32x8 B1 = frag(Bb, rowB + 32, kb0);
    i32x8 A2 = frag(Ab, rowA + 64, kb0);
    i32x8 A3 = frag(Ab, rowA + 96, kb0);
    LGKM(4);
    acc[0][0] = mx(A0, B0, acc[0][0]);  acc[0][1] = mx(A0, B1, acc[0][1]);
    acc[1][0] = mx(A1, B0, acc[1][0]);  acc[1][1] = mx(A1, B1, acc[1][1]);
    i32x8 A0p = frag(Ab, rowA +  0, kb1);
    i32x8 A1p = frag(Ab, rowA + 32, kb1);
    i32x8 B0p = frag(Bb, rowB +  0, kb1);
    i32x8 B1p = frag(Bb, rowB + 32, kb1);
    LGKM(8);
    acc[2][0] = mx(A2, B0, acc[2][0]);  acc[2][1] = mx(A2, B1, acc[2][1]);
    acc[3][0] = mx(A3, B0, acc[3][0]);  acc[3][1] = mx(A3, B1, acc[3][1]);
    i32x8 A2p = frag(Ab, rowA + 64, kb1);
    i32x8 A3p = frag(Ab, rowA + 96, kb1);
    LGKM(4);
    acc[0][0] = mx(A0p, B0p, acc[0][0]);  acc[0][1] = mx(A0p, B1p, acc[0][1]);
    acc[1][0] = mx(A1p, B0p, acc[1][0]);  acc[1][1] = mx(A1p, B1p, acc[1][1]);
    LGKM(0);
    acc[2][0] = mx(A2p, B0p, acc[2][0]);  acc[2][1] = mx(A2p, B1p, acc[2][1]);
    acc[3][0] = mx(A3p, B0p, acc[3][0]);  acc[3][1] = mx(A3p, B1p, acc[3][1]);
  }

  // Epilogue.  C/D layout (32x32, dtype-independent): col = lane&31,
  // row = (r&3) + 8*(r>>2) + 4*kh, r in [0,16).
  const float alpha = iscale[0] * wscale[0];
  const long long col0 = tile_n + wn * 64 + col;
  const float bv0 = bias[col0];
  const float bv1 = bias[col0 + 32];
#pragma unroll
  for (int m = 0; m < 4; ++m) {
#pragma unroll
    for (int r = 0; r < 16; ++r) {
      const long long row =
          tile_m + wm * 128 + m * 32 + (r & 3) + 8 * (r >> 2) + 4 * kh;
      float* op = out + row * (long long)Ndim + col0;
      op[0]  = acc[m][0][r] * alpha + bv0;
      op[32] = acc[m][1][r] * alpha + bv1;
    }
  }
#undef STAGE
}

extern "C" void kernel_launch(void* const* d_in, const int* in_sizes, int n_in,
                              void* d_out, int out_size, void* d_ws, size_t ws_size,
                              hipStream_t stream) {
  const float* x      = (const float*)d_in[0];  // [4,2048,4096]
  const float* weight = (const float*)d_in[1];  // [14336,4096] (e4m3 lattice)
  const float* wscale = (const float*)d_in[2];  // [1]
  const float* iscale = (const float*)d_in[3];  // [1]
  const float* bias   = (const float*)d_in[4];  // [14336]
  float* out = (float*)d_out;                   // [4,2048,14336]

  uint8_t* qx = (uint8_t*)d_ws;                          // 32 MiB
  uint8_t* qw = qx + (long long)Mdim * Kdim;             // 56 MiB

  const long long nx = (long long)Mdim * Kdim;
  const long long nw = (long long)Ndim * Kdim;

  quant_fp8_kernel<<<4096, 256, 0, stream>>>(x, qx, iscale, nx);
  quant_fp8_kernel<<<4096, 256, 0, stream>>>(weight, qw, nullptr, nw);

  dim3 grid(Ndim / BN, Mdim / BM);   // 56 x 32
  gemm_fp8_kernel<<<grid, 512, 0, stream>>>(qx, qw, iscale, wscale, bias, out);
}